// Round 3
// baseline (219.256 us; speedup 1.0000x reference)
//
#include <hip/hip_runtime.h>

// LinearAutoDecoder: rgb[n,j] = dot(X[n,:], w_cat[3*cid[n]+j, :]), DIM=319.
// Strategy: 16 rows/block staged to LDS via global_load_lds (width 16) --
// 16*319 floats is 16B-aligned per block, so all X traffic is dwordx4.
// Per-row float4 phase d=(ri*319)&3 handled by 4 pre-shifted weight tables
// built into d_ws (972 KB, L2-resident). Reduction on VALU via DPP.

constexpr int POS = 63;
constexpr int LAT = 256;
constexpr int DIM = POS + LAT;   // 319
constexpr int NCH = 192;         // 3 * 64 clusters
constexpr int SLOTS = 81;        // float4 slots per (d, ch) table row
constexpr int RPB = 16;          // rows per block
constexpr int LDS_SLOTS = RPB * DIM / 4;  // 1276
constexpr size_t WTAB_BYTES = (size_t)4 * NCH * SLOTS * 16;  // 995,328 B

// ---------- init: shifted weight tables in workspace ----------
// ws4[(d*NCH + ch)*SLOTS + sl][c] = w_cat(ch, 4*sl + c - d), 0 outside [0,319)
__global__ __launch_bounds__(256) void build_wtab(
    const float* __restrict__ Wp,   // [192, 63]
    const float* __restrict__ Wf,   // [192, 256]
    float4* __restrict__ ws4)
{
    const int idx = blockIdx.x * 256 + threadIdx.x;   // one float4 per thread
    const int total = 4 * NCH * SLOTS;                // 62208
    if (idx >= total) return;
    const int sl = idx % SLOTS;
    const int t  = idx / SLOTS;
    const int ch = t % NCH;
    const int d  = t / NCH;
    float v[4];
#pragma unroll
    for (int c = 0; c < 4; ++c) {
        const int k = 4 * sl + c - d;
        float w = 0.f;
        if (k >= 0 && k < POS)            w = Wp[ch * POS + k];
        else if (k >= POS && k < DIM)     w = Wf[ch * LAT + (k - POS)];
        v[c] = w;
    }
    ws4[idx] = make_float4(v[0], v[1], v[2], v[3]);
}

// ---------- DPP wave64 sum (pure VALU), result valid in lane 63 ----------
template <int CTRL>
__device__ __forceinline__ float dpp_add_step(float x) {
    int s = __builtin_amdgcn_update_dpp(0, __float_as_int(x), CTRL,
                                        0xF, 0xF, /*bound_ctrl=*/true);
    return x + __int_as_float(s);
}
__device__ __forceinline__ float wave_reduce_sum(float x) {
    x = dpp_add_step<0x111>(x);  // row_shr:1
    x = dpp_add_step<0x112>(x);  // row_shr:2
    x = dpp_add_step<0x114>(x);  // row_shr:4
    x = dpp_add_step<0x118>(x);  // row_shr:8
    x = dpp_add_step<0x142>(x);  // row_bcast15
    x = dpp_add_step<0x143>(x);  // row_bcast31
    return x;
}

// ---------- main kernel ----------
__global__ __launch_bounds__(256) void lad_fast(
    const float* __restrict__ X,
    const int*   __restrict__ cid,
    const float4* __restrict__ ws4,  // shifted weight tables
    float*       __restrict__ out,
    int n)
{
    __shared__ float4 xs[LDS_SLOTS];  // 20416 B -> 8 blocks/CU

    const int r0 = blockIdx.x * RPB;
    const size_t xbytes_total = (size_t)n * DIM * 4;
    const char* gbase = (const char*)X + (size_t)r0 * DIM * 4;  // 16B aligned

    // Stage 16 rows (5104 floats) linearly: 5 global_load_lds width-16 per thread.
    const int t = threadIdx.x;
#pragma unroll
    for (int i = 0; i < 5; ++i) {
        const int slot = i * 256 + t;
        if (slot < LDS_SLOTS) {
            size_t goff = (size_t)r0 * DIM * 4 + (size_t)slot * 16;
            const char* gp = (const char*)X + goff;
            if (goff + 16 > xbytes_total)                  // tail block guard
                gp = (const char*)X + (xbytes_total - 16);
            __builtin_amdgcn_global_load_lds(
                (const __attribute__((address_space(1))) unsigned int*)gp,
                (__attribute__((address_space(3))) unsigned int*)&xs[slot],
                16, 0, 0);
        }
    }
    __syncthreads();

    const int w = threadIdx.x >> 6;
    const int l = threadIdx.x & 63;

    // Each wave computes 4 consecutive rows.
    for (int q = 0; q < 4; ++q) {
        const int ri = w * 4 + q;
        const int r  = r0 + ri;
        if (r >= n) break;

        const int off = ri * DIM;        // float offset of row in LDS
        const int d   = off & 3;         // phase: 0,3,2,1 repeating
        const int s0  = off >> 2;        // first float4 slot
        const int p2n = d ? 17 : 16;     // second-pass active lanes

        const int c3 = 3 * cid[r];
        const float4* wt = ws4 + (size_t)(d * NCH + c3) * SLOTS;

        const float4 xa = xs[s0 + l];
        const bool m2 = (l < p2n);
        float4 xb;
        if (m2) xb = xs[s0 + 64 + l];

        float acc[3];
#pragma unroll
        for (int j = 0; j < 3; ++j) {
            const float4* wr = wt + (size_t)j * SLOTS;
            const float4 wa = wr[l];
            float a = xa.x * wa.x + xa.y * wa.y + xa.z * wa.z + xa.w * wa.w;
            if (m2) {
                const float4 wb = wr[64 + l];
                a += xb.x * wb.x + xb.y * wb.y + xb.z * wb.z + xb.w * wb.w;
            }
            acc[j] = wave_reduce_sum(a);
        }
        if (l == 63) {
            float* o = out + (size_t)r * 3;
            o[0] = acc[0];
            o[1] = acc[1];
            o[2] = acc[2];
        }
    }
}

// ---------- fallback (R2 kernel) if workspace is too small ----------
__global__ __launch_bounds__(256) void lad_fallback(
    const float* __restrict__ X,
    const int*   __restrict__ cid,
    const float* __restrict__ Wp,
    const float* __restrict__ Wf,
    float*       __restrict__ out,
    int n)
{
    const int lane = threadIdx.x & 63;
    const int wave = (int)((blockIdx.x * blockDim.x + threadIdx.x) >> 6);
    if (wave >= n) return;
    const size_t row = (size_t)wave;
    const float* xrow = X + row * (size_t)DIM;
    const float* xf   = xrow + POS;
    const int c3 = cid[row] * 3;
    const float* wp0 = Wp + (size_t)c3 * POS;
    const float* wf0 = Wf + (size_t)c3 * LAT;
    float a0 = 0.f, a1 = 0.f, a2 = 0.f;
#pragma unroll
    for (int i = 0; i < 4; ++i) {
        const int k = lane + 64 * i;
        const float x = xf[k];
        a0 = fmaf(x, wf0[k], a0);
        a1 = fmaf(x, wf0[k + LAT], a1);
        a2 = fmaf(x, wf0[k + 2 * LAT], a2);
    }
    if (lane < POS) {
        const float x = xrow[lane];
        a0 = fmaf(x, wp0[lane], a0);
        a1 = fmaf(x, wp0[lane + POS], a1);
        a2 = fmaf(x, wp0[lane + 2 * POS], a2);
    }
    a0 = wave_reduce_sum(a0);
    a1 = wave_reduce_sum(a1);
    a2 = wave_reduce_sum(a2);
    if (lane == 63) {
        float* o = out + row * 3;
        o[0] = a0; o[1] = a1; o[2] = a2;
    }
}

extern "C" void kernel_launch(void* const* d_in, const int* in_sizes, int n_in,
                              void* d_out, int out_size, void* d_ws, size_t ws_size,
                              hipStream_t stream) {
    const float* X   = (const float*)d_in[0];
    const int*   cid = (const int*)d_in[1];
    const float* Wp  = (const float*)d_in[2];
    const float* Wf  = (const float*)d_in[3];
    float* out = (float*)d_out;
    const int n = in_sizes[1];

    if (ws_size >= WTAB_BYTES) {
        float4* ws4 = (float4*)d_ws;
        // 62208 table entries -> 243 blocks of 256.
        build_wtab<<<243, 256, 0, stream>>>(Wp, Wf, ws4);
        const int blocks = (n + RPB - 1) / RPB;
        lad_fast<<<blocks, 256, 0, stream>>>(X, cid, ws4, out, n);
    } else {
        const int blocks = (n + 3) / 4;
        lad_fallback<<<blocks, 256, 0, stream>>>(X, cid, Wp, Wf, out, n);
    }
}